// Round 2
// baseline (1111.591 us; speedup 1.0000x reference)
//
#include <hip/hip_runtime.h>
#include <math.h>

#define P 64
#define WAVES_PER_BLOCK 4

__global__ __launch_bounds__(256) void minibank_kernel(
    const float* __restrict__ C,
    const float* __restrict__ W1,
    const float* __restrict__ b1,
    const float* __restrict__ Wp,
    const float* __restrict__ bp,
    float* __restrict__ out,
    int N, float scale)
{
    const int wave = threadIdx.x >> 6;
    const int lane = threadIdx.x & 63;
    const int n = blockIdx.x * WAVES_PER_BLOCK + wave;
    if (n >= N) return;

    __shared__ float ct_lds[WAVES_PER_BLOCK][P];

    // ---- Step A: softmax(scale * C[n][:]) across the wave (lane = element) ----
    float x = C[(size_t)n * P + lane] * scale;
    float m = x;
    #pragma unroll
    for (int off = 32; off > 0; off >>= 1)
        m = fmaxf(m, __shfl_xor(m, off, 64));
    float e = expf(x - m);
    float s = e;
    #pragma unroll
    for (int off = 32; off > 0; off >>= 1)
        s += __shfl_xor(s, off, 64);
    float ct = e / s;
    ct_lds[wave][lane] = ct;   // intra-wave LDS write->read; compiler inserts lgkmcnt wait
    // no __syncthreads needed: each wave touches only its own LDS row

    // ---- Step B: c_star[o] = relu(dot(W1[n][o][:], ct) + b1[n][o]), lane = o ----
    const float4* w1row =
        reinterpret_cast<const float4*>(W1 + (size_t)n * P * P + (size_t)lane * P);
    const float4* ctv = reinterpret_cast<const float4*>(ct_lds[wave]);
    float acc = b1[(size_t)n * P + lane];
    #pragma unroll
    for (int j = 0; j < P / 4; ++j) {
        float4 w = w1row[j];
        float4 c4 = ctv[j];            // uniform-address ds_read_b128 broadcast
        acc += w.x * c4.x;
        acc += w.y * c4.y;
        acc += w.z * c4.z;
        acc += w.w * c4.w;
    }
    float cs = fmaxf(acc, 0.0f);

    // ---- Probability head: 2 logits via wave reductions ----
    const float* wp = Wp + (size_t)n * 2 * P;
    float r0 = wp[lane] * cs;
    float r1 = wp[P + lane] * cs;
    #pragma unroll
    for (int off = 32; off > 0; off >>= 1) {
        r0 += __shfl_xor(r0, off, 64);
        r1 += __shfl_xor(r1, off, 64);
    }
    float l0 = r0 + bp[(size_t)n * 2 + 0];
    float l1 = r1 + bp[(size_t)n * 2 + 1];
    float mm = fmaxf(l0, l1);
    float e0 = expf(l0 - mm);
    float e1 = expf(l1 - mm);
    float inv = 1.0f / (e0 + e1);
    float p0 = e0 * inv;
    float p1 = e1 * inv;

    // ---- Step C: tanh-combine, coalesced store ----
    out[(size_t)n * P + lane] = tanhf(p0 * cs) + tanhf(p1 * cs);
}

extern "C" void kernel_launch(void* const* d_in, const int* in_sizes, int n_in,
                              void* d_out, int out_size, void* d_ws, size_t ws_size,
                              hipStream_t stream) {
    const float* C  = (const float*)d_in[0];
    const float* W1 = (const float*)d_in[1];
    const float* b1 = (const float*)d_in[2];
    const float* Wp = (const float*)d_in[3];
    const float* bp = (const float*)d_in[4];
    float* out = (float*)d_out;

    const int N = in_sizes[0] / P;       // C is [N, P]
    const float scale = (float)N;        // n_pers in the reference

    const int blocks = (N + WAVES_PER_BLOCK - 1) / WAVES_PER_BLOCK;
    minibank_kernel<<<blocks, 256, 0, stream>>>(C, W1, b1, Wp, bp, out, N, scale);
}

// Round 3
// 1038.051 us; speedup vs baseline: 1.0708x; 1.0708x over previous
//
#include <hip/hip_runtime.h>
#include <math.h>

#define P 64
#define WAVES_PER_BLOCK 4

// One wave per model. W1 is read fully coalesced: wave-instruction j loads the
// contiguous 1KB slab covering rows 4j..4j+3 of W1[n]; each 16-lane group owns
// one row (lane holds 4 cols), dot via 4x shfl_xor intra-group reduce.
__global__ __launch_bounds__(256) void minibank_kernel(
    const float* __restrict__ C,
    const float* __restrict__ W1,
    const float* __restrict__ b1,
    const float* __restrict__ Wp,
    const float* __restrict__ bp,
    float* __restrict__ out,
    int N, float scale)
{
    const int wave = threadIdx.x >> 6;
    const int lane = threadIdx.x & 63;
    const int n = blockIdx.x * WAVES_PER_BLOCK + wave;
    if (n >= N) return;

    __shared__ float ct_lds[WAVES_PER_BLOCK][P];
    __shared__ float cs_lds[WAVES_PER_BLOCK][P];

    // ---- Step A: softmax(scale * C[n][:]) across the wave (lane = element) ----
    float x = C[(size_t)n * P + lane] * scale;
    float m = x;
    #pragma unroll
    for (int off = 32; off > 0; off >>= 1)
        m = fmaxf(m, __shfl_xor(m, off, 64));
    float e = expf(x - m);
    float s = e;
    #pragma unroll
    for (int off = 32; off > 0; off >>= 1)
        s += __shfl_xor(s, off, 64);
    float ct = e / s;
    ct_lds[wave][lane] = ct;   // same-wave LDS; compiler inserts lgkmcnt wait

    // lane i consumes ct[(i&15)*4 .. +3] for every j (columns it owns).
    // 16 distinct addrs x4-lane broadcast -> conflict-free.
    const float4 ct4 = *reinterpret_cast<const float4*>(&ct_lds[wave][(lane & 15) * 4]);

    // ---- Step B: coalesced W1 matvec ----
    const float4* __restrict__ w1 =
        reinterpret_cast<const float4*>(W1 + (size_t)n * P * P);
    const int g = lane >> 4;
    #pragma unroll
    for (int j = 0; j < 16; ++j) {
        float4 w = w1[j * 64 + lane];               // 1KB contiguous per wave inst
        float s4 = w.x * ct4.x + w.y * ct4.y + w.z * ct4.z + w.w * ct4.w;
        s4 += __shfl_xor(s4, 1, 64);                // intra-16-lane tree reduce
        s4 += __shfl_xor(s4, 2, 64);
        s4 += __shfl_xor(s4, 4, 64);
        s4 += __shfl_xor(s4, 8, 64);
        if ((lane & 15) == 0) cs_lds[wave][4 * j + g] = s4;   // row 4j+g
    }

    float cs = fmaxf(cs_lds[wave][lane] + b1[(size_t)n * P + lane], 0.0f);

    // ---- Probability head: 2 logits via wave reductions (coalesced Wp reads) ----
    const float* __restrict__ wp = Wp + (size_t)n * 2 * P;
    float r0 = wp[lane] * cs;
    float r1 = wp[P + lane] * cs;
    #pragma unroll
    for (int off = 32; off > 0; off >>= 1) {
        r0 += __shfl_xor(r0, off, 64);
        r1 += __shfl_xor(r1, off, 64);
    }
    float l0 = r0 + bp[(size_t)n * 2 + 0];
    float l1 = r1 + bp[(size_t)n * 2 + 1];
    float mm = fmaxf(l0, l1);
    float e0 = expf(l0 - mm);
    float e1 = expf(l1 - mm);
    float inv = 1.0f / (e0 + e1);
    float p0 = e0 * inv;
    float p1 = e1 * inv;

    // ---- Step C: tanh-combine, coalesced store ----
    out[(size_t)n * P + lane] = tanhf(p0 * cs) + tanhf(p1 * cs);
}

extern "C" void kernel_launch(void* const* d_in, const int* in_sizes, int n_in,
                              void* d_out, int out_size, void* d_ws, size_t ws_size,
                              hipStream_t stream) {
    const float* C  = (const float*)d_in[0];
    const float* W1 = (const float*)d_in[1];
    const float* b1 = (const float*)d_in[2];
    const float* Wp = (const float*)d_in[3];
    const float* bp = (const float*)d_in[4];
    float* out = (float*)d_out;

    const int N = in_sizes[0] / P;       // C is [N, P]
    const float scale = (float)N;        // n_pers in the reference

    const int blocks = (N + WAVES_PER_BLOCK - 1) / WAVES_PER_BLOCK;
    minibank_kernel<<<blocks, 256, 0, stream>>>(C, W1, b1, Wp, bp, out, N, scale);
}